// Round 1
// baseline (358.780 us; speedup 1.0000x reference)
//
#include <hip/hip_runtime.h>
#include <cstdint>
#include <cstddef>

typedef unsigned short u16;
typedef __attribute__((ext_vector_type(8))) short bf16x8;
typedef __attribute__((ext_vector_type(4))) float f32x4;

__device__ __forceinline__ u16 f2bf(float f) {
  union { float f; unsigned int u; } v; v.f = f;
  unsigned int r = v.u + 0x7fffu + ((v.u >> 16) & 1u);
  return (u16)(r >> 16);
}

__device__ __forceinline__ void glds16(const void* g, void* l) {
  __builtin_amdgcn_global_load_lds(
      (const __attribute__((address_space(1))) unsigned int*)g,
      (__attribute__((address_space(3))) unsigned int*)l, 16, 0, 0);
}

__device__ __forceinline__ f32x4 fzero4() { f32x4 z = {0.f, 0.f, 0.f, 0.f}; return z; }

// ---------------- conversion: x,y f32 -> bf16 (vectorized) ----------------
__global__ void cvt_kernel(const float* __restrict__ x, u16* __restrict__ xb,
                           const float* __restrict__ y, u16* __restrict__ yb, int n4) {
  int i = blockIdx.x * blockDim.x + threadIdx.x;
  const float* src; u16* dst;
  if (i < n4) { src = x; dst = xb; }
  else        { src = y; dst = yb; i -= n4; }
  float4 v = ((const float4*)src)[i];
  ushort4 o = make_ushort4(f2bf(v.x), f2bf(v.y), f2bf(v.z), f2bf(v.w));
  ((ushort4*)dst)[i] = o;
}

// ---------------- transpose + convert: W [K][N] f32 -> Wt [N][K] bf16 ----------------
__global__ void transcvt_kernel(const float* __restrict__ in, u16* __restrict__ out,
                                int K, int N) {
  __shared__ float tile[32][33];
  int n0 = blockIdx.x * 32, k0 = blockIdx.y * 32;
  int tx = threadIdx.x & 31, ty = threadIdx.x >> 5;  // 256 threads: 32x8
  #pragma unroll
  for (int j = ty; j < 32; j += 8) tile[j][tx] = in[(size_t)(k0 + j) * N + n0 + tx];
  __syncthreads();
  #pragma unroll
  for (int j = ty; j < 32; j += 8) out[(size_t)(n0 + j) * K + k0 + tx] = f2bf(tile[tx][j]);
}

// ---------------- GEMM: out[M][N] = A[M][K] @ Bt[N][K]^T + bias ----------------
// LDS k-chunked layout: chunk c = quad*128 + row, 8 bf16 (16B) per chunk.
__device__ __forceinline__ void gemm_body(u16* lA, u16* lB,
    const u16* __restrict__ A, const u16* __restrict__ Bt,
    const float* __restrict__ bias, u16* __restrict__ out,
    int K, int N, int outmode) {
  const int tid = threadIdx.x, wave = tid >> 6, lane = tid & 63;
  const int quadL = lane >> 4, l16 = lane & 15;
  const int row0 = blockIdx.y * 128, col0 = blockIdx.x * 128;
  const int wm = (wave >> 1) * 64, wn = (wave & 1) * 64;

  f32x4 acc[4][4];
  #pragma unroll
  for (int i = 0; i < 4; i++)
    #pragma unroll
    for (int j = 0; j < 4; j++) acc[i][j] = fzero4();

  for (int k0 = 0; k0 < K; k0 += 32) {
    __syncthreads();
    #pragma unroll
    for (int i = 0; i < 4; i++) {
      int inst = wave * 4 + i;
      if (inst < 8) {
        int c = inst * 64 + lane;
        glds16(A + (size_t)(row0 + (c & 127)) * K + k0 + (c >> 7) * 8, lA + inst * 512);
      } else {
        int i2 = inst - 8;
        int c = i2 * 64 + lane;
        glds16(Bt + (size_t)(col0 + (c & 127)) * K + k0 + (c >> 7) * 8, lB + i2 * 512);
      }
    }
    __syncthreads();
    bf16x8 af[4], bfr[4];
    #pragma unroll
    for (int mi = 0; mi < 4; mi++)
      af[mi] = *(const bf16x8*)(lA + (quadL * 128 + wm + mi * 16 + l16) * 8);
    #pragma unroll
    for (int ni = 0; ni < 4; ni++)
      bfr[ni] = *(const bf16x8*)(lB + (quadL * 128 + wn + ni * 16 + l16) * 8);
    #pragma unroll
    for (int mi = 0; mi < 4; mi++)
      #pragma unroll
      for (int ni = 0; ni < 4; ni++)
        acc[mi][ni] = __builtin_amdgcn_mfma_f32_16x16x32_bf16(af[mi], bfr[ni], acc[mi][ni], 0, 0, 0);
  }

  #pragma unroll
  for (int mi = 0; mi < 4; mi++)
    #pragma unroll
    for (int ni = 0; ni < 4; ni++) {
      int col = col0 + wn + ni * 16 + l16;
      float bvv = bias[col];
      #pragma unroll
      for (int r = 0; r < 4; r++) {
        int row = row0 + wm + mi * 16 + quadL * 4 + r;
        float v = acc[mi][ni][r] + bvv;
        if (outmode == 0) {
          out[(size_t)row * N + col] = f2bf(v);
        } else {
          // ht[b][head][dv][m]  (head = col>>7, dv = col&127; b = row>>11, m = row&2047)
          int bb = row >> 11, mloc = row & 2047;
          int head = col >> 7, dv = col & 127;
          out[((size_t)((bb * 8 + head) * 128 + dv)) * 2048 + mloc] = f2bf(v);
        }
      }
    }
}

__global__ __launch_bounds__(256, 2)
void gemm_qk_kernel(const u16* __restrict__ xb, const u16* __restrict__ yb,
                    const u16* __restrict__ wqt, const u16* __restrict__ wkt,
                    const float* __restrict__ bq, const float* __restrict__ bk,
                    u16* __restrict__ fb, u16* __restrict__ gb) {
  __shared__ __align__(16) u16 lA[4096];
  __shared__ __align__(16) u16 lB[4096];
  if (blockIdx.z == 0) gemm_body(lA, lB, xb, wqt, bq, fb, 1024, 256, 0);
  else                 gemm_body(lA, lB, yb, wkt, bk, gb, 1024, 256, 0);
}

__global__ __launch_bounds__(256, 2)
void gemm_v_kernel(const u16* __restrict__ yb, const u16* __restrict__ wvt,
                   const float* __restrict__ bv, u16* __restrict__ ht) {
  __shared__ __align__(16) u16 lA[4096];
  __shared__ __align__(16) u16 lB[4096];
  gemm_body(lA, lB, yb, wvt, bv, ht, 1024, 1024, 1);
}

// ---------------- flash attention ----------------
// Grid: (M/64, H, B). Block: 256 threads (4 waves, 16 Q-rows each).
__global__ __launch_bounds__(256, 2)
void attn_kernel(const u16* __restrict__ fb, const u16* __restrict__ gb,
                 const u16* __restrict__ ht, const float* __restrict__ x,
                 const float* __restrict__ gamma, float* __restrict__ out) {
  __shared__ __align__(16) u16 lK[4096];        // 8KB, chunks [quad][n]
  __shared__ __align__(16) u16 lV[16384];       // 32KB, chunks [n/8][dv]
  __shared__ __align__(16) u16 lP[4 * 16 * 136];// per-wave P tile, stride 136
  const int tid = threadIdx.x, wave = tid >> 6, lane = tid & 63;
  const int quadL = lane >> 4, l16 = lane & 15;
  const int m0 = blockIdx.x * 64;
  const int head = blockIdx.y;
  const int b = blockIdx.z;

  // Q fragment (A-layout): row = m0+wave*16+l16, d = quadL*8..+8
  const int qrow = m0 + wave * 16 + l16;
  bf16x8 qf = *(const bf16x8*)(fb + ((size_t)(b * 2048 + qrow) * 256 + head * 32 + quadL * 8));

  f32x4 oacc[8];
  #pragma unroll
  for (int t = 0; t < 8; t++) oacc[t] = fzero4();
  float mrow[4], lrow[4];
  #pragma unroll
  for (int r = 0; r < 4; r++) { mrow[r] = -3.0e38f; lrow[r] = 0.f; }

  const float sscale = 0.17677669529663687f * 1.4426950408889634f;  // 1/sqrt(32)*log2(e)
  u16* pw = lP + wave * (16 * 136);

  for (int n0 = 0; n0 < 2048; n0 += 128) {
    __syncthreads();
    #pragma unroll
    for (int i = 0; i < 10; i++) {
      int inst = wave * 10 + i;
      if (inst < 8) {
        int c = inst * 64 + lane;
        glds16(gb + ((size_t)(b * 2048 + n0 + (c & 127)) * 256 + head * 32 + (c >> 7) * 8),
               lK + inst * 512);
      } else {
        int i2 = inst - 8;
        int c = i2 * 64 + lane;
        glds16(ht + ((size_t)((b * 8 + head) * 128 + (c & 127)) * 2048 + n0 + (c >> 7) * 8),
               lV + i2 * 512);
      }
    }
    __syncthreads();

    // S = Q K^T for this wave's 16x128 stripe; leaky-relu + scale in log2 domain
    float pv[8][4];
    float vmax[4] = {-3.0e38f, -3.0e38f, -3.0e38f, -3.0e38f};
    #pragma unroll
    for (int t = 0; t < 8; t++) {
      bf16x8 kf = *(const bf16x8*)(lK + (quadL * 128 + t * 16 + l16) * 8);
      f32x4 s = __builtin_amdgcn_mfma_f32_16x16x32_bf16(qf, kf, fzero4(), 0, 0, 0);
      #pragma unroll
      for (int r = 0; r < 4; r++) {
        float sv = s[r];
        float v = sv * sscale;
        v = (sv >= 0.f) ? v : 0.2f * v;
        pv[t][r] = v;
        vmax[r] = fmaxf(vmax[r], v);
      }
    }
    #pragma unroll
    for (int off = 1; off < 16; off <<= 1)
      #pragma unroll
      for (int r = 0; r < 4; r++)
        vmax[r] = fmaxf(vmax[r], __shfl_xor(vmax[r], off, 64));

    float alpha[4], rsum[4];
    #pragma unroll
    for (int r = 0; r < 4; r++) {
      float mn = fmaxf(mrow[r], vmax[r]);
      alpha[r] = exp2f(mrow[r] - mn);
      mrow[r] = mn;
      rsum[r] = 0.f;
    }
    #pragma unroll
    for (int t = 0; t < 8; t++)
      #pragma unroll
      for (int r = 0; r < 4; r++) {
        float p = exp2f(pv[t][r] - mrow[r]);
        pv[t][r] = p;
        rsum[r] += p;
      }
    #pragma unroll
    for (int off = 1; off < 16; off <<= 1)
      #pragma unroll
      for (int r = 0; r < 4; r++)
        rsum[r] += __shfl_xor(rsum[r], off, 64);
    #pragma unroll
    for (int r = 0; r < 4; r++) lrow[r] = lrow[r] * alpha[r] + rsum[r];
    #pragma unroll
    for (int t = 0; t < 8; t++)
      #pragma unroll
      for (int r = 0; r < 4; r++) oacc[t][r] *= alpha[r];

    // P (C-layout) -> LDS -> A-layout fragments
    #pragma unroll
    for (int t = 0; t < 8; t++)
      #pragma unroll
      for (int r = 0; r < 4; r++)
        pw[(quadL * 4 + r) * 136 + t * 16 + l16] = f2bf(pv[t][r]);

    #pragma unroll
    for (int kt = 0; kt < 4; kt++) {
      bf16x8 pf = *(const bf16x8*)(pw + l16 * 136 + kt * 32 + quadL * 8);
      #pragma unroll
      for (int tdv = 0; tdv < 8; tdv++) {
        bf16x8 vf = *(const bf16x8*)(lV + ((kt * 4 + quadL) * 128 + tdv * 16 + l16) * 8);
        oacc[tdv] = __builtin_amdgcn_mfma_f32_16x16x32_bf16(pf, vf, oacc[tdv], 0, 0, 0);
      }
    }
  }

  const float gam = gamma[0];
  float invl[4];
  #pragma unroll
  for (int r = 0; r < 4; r++) invl[r] = 1.0f / lrow[r];
  #pragma unroll
  for (int tdv = 0; tdv < 8; tdv++)
    #pragma unroll
    for (int r = 0; r < 4; r++) {
      int row = m0 + wave * 16 + quadL * 4 + r;
      int col = head * 128 + tdv * 16 + l16;
      size_t idx = ((size_t)(b * 2048 + row)) * 1024 + col;
      out[idx] = gam * (oacc[tdv][r] * invl[r]) + x[idx];
    }
}

extern "C" void kernel_launch(void* const* d_in, const int* in_sizes, int n_in,
                              void* d_out, int out_size, void* d_ws, size_t ws_size,
                              hipStream_t stream) {
  const float* x     = (const float*)d_in[0];
  const float* y     = (const float*)d_in[1];
  const float* Wq    = (const float*)d_in[2];
  const float* bq    = (const float*)d_in[3];
  const float* Wk    = (const float*)d_in[4];
  const float* bk    = (const float*)d_in[5];
  const float* Wv    = (const float*)d_in[6];
  const float* bv    = (const float*)d_in[7];
  const float* gamma = (const float*)d_in[8];
  float* out = (float*)d_out;

  char* ws = (char*)d_ws;
  u16* xb  = (u16*)(ws);                 // 16 MB
  u16* yb  = (u16*)(ws + 16777216);      // 16 MB
  u16* wqt = (u16*)(ws + 33554432);      // 0.5 MB  [256][1024]
  u16* wkt = (u16*)(ws + 34078720);      // 0.5 MB
  u16* wvt = (u16*)(ws + 34603008);      // 2 MB    [1024][1024]
  u16* fb  = (u16*)(ws + 36700160);      // 4 MB    [B*M][256]
  u16* gb  = (u16*)(ws + 40894464);      // 4 MB
  u16* ht  = (u16*)(ws + 45088768);      // 16 MB   [B][H][DV][M]

  // x,y -> bf16 (both in one launch; 2*2097152 float4 groups)
  cvt_kernel<<<16384, 256, 0, stream>>>(x, xb, y, yb, 2097152);
  // weights -> transposed bf16
  transcvt_kernel<<<dim3(8, 32), 256, 0, stream>>>(Wq, wqt, 1024, 256);
  transcvt_kernel<<<dim3(8, 32), 256, 0, stream>>>(Wk, wkt, 1024, 256);
  transcvt_kernel<<<dim3(32, 32), 256, 0, stream>>>(Wv, wvt, 1024, 1024);
  // projections
  gemm_qk_kernel<<<dim3(2, 64, 2), 256, 0, stream>>>(xb, yb, wqt, wkt, bq, bk, fb, gb);
  gemm_v_kernel<<<dim3(8, 64), 256, 0, stream>>>(yb, wvt, bv, ht);
  // fused attention + residual
  attn_kernel<<<dim3(32, 8, 4), 256, 0, stream>>>(fb, gb, ht, x, gamma, out);
}

// Round 2
// 291.412 us; speedup vs baseline: 1.2312x; 1.2312x over previous
//
#include <hip/hip_runtime.h>
#include <cstdint>
#include <cstddef>

typedef unsigned short u16;
typedef unsigned int u32;
typedef __attribute__((ext_vector_type(8))) short bf16x8;
typedef __attribute__((ext_vector_type(4))) float f32x4;

__device__ __forceinline__ u16 f2bf(float f) {
  union { float f; unsigned int u; } v; v.f = f;
  unsigned int r = v.u + 0x7fffu + ((v.u >> 16) & 1u);
  return (u16)(r >> 16);
}

__device__ __forceinline__ u32 pack_bf_trunc(float hi, float lo) {
#if __has_builtin(__builtin_amdgcn_perm)
  return __builtin_amdgcn_perm(__float_as_uint(hi), __float_as_uint(lo), 0x07060302u);
#else
  return (__float_as_uint(hi) & 0xffff0000u) | (__float_as_uint(lo) >> 16);
#endif
}

__device__ __forceinline__ void glds16(const void* g, void* l) {
  __builtin_amdgcn_global_load_lds(
      (const __attribute__((address_space(1))) unsigned int*)g,
      (__attribute__((address_space(3))) unsigned int*)l, 16, 0, 0);
}

__device__ __forceinline__ f32x4 fzero4() { f32x4 z = {0.f, 0.f, 0.f, 0.f}; return z; }

// ---------------- conversion: x,y f32 -> bf16 (vectorized) ----------------
__global__ void cvt_kernel(const float* __restrict__ x, u16* __restrict__ xb,
                           const float* __restrict__ y, u16* __restrict__ yb, int n4) {
  int i = blockIdx.x * blockDim.x + threadIdx.x;
  const float* src; u16* dst;
  if (i < n4) { src = x; dst = xb; }
  else        { src = y; dst = yb; i -= n4; }
  float4 v = ((const float4*)src)[i];
  ushort4 o = make_ushort4(f2bf(v.x), f2bf(v.y), f2bf(v.z), f2bf(v.w));
  ((ushort4*)dst)[i] = o;
}

// ---------------- transpose + convert: W [K][N] f32 -> Wt [N][K] bf16 ----------------
__global__ void transcvt_kernel(const float* __restrict__ in, u16* __restrict__ out,
                                int K, int N) {
  __shared__ float tile[32][33];
  int n0 = blockIdx.x * 32, k0 = blockIdx.y * 32;
  int tx = threadIdx.x & 31, ty = threadIdx.x >> 5;  // 256 threads: 32x8
  #pragma unroll
  for (int j = ty; j < 32; j += 8) tile[j][tx] = in[(size_t)(k0 + j) * N + n0 + tx];
  __syncthreads();
  #pragma unroll
  for (int j = ty; j < 32; j += 8) out[(size_t)(n0 + j) * K + k0 + tx] = f2bf(tile[tx][j]);
}

// ---------------- fused projection GEMM ----------------
// out tiles over [8192][1536]: cols 0-255 -> fb (Q), 256-511 -> gb (K),
// 512-1535 -> ht (V, stored [b][head][dv][m]).
__global__ __launch_bounds__(256, 3)
void gemm_all_kernel(const u16* __restrict__ xb, const u16* __restrict__ yb,
                     const u16* __restrict__ wt,
                     const float* __restrict__ bq, const float* __restrict__ bk,
                     const float* __restrict__ bv,
                     u16* __restrict__ fb, u16* __restrict__ gb, u16* __restrict__ ht) {
  __shared__ __align__(16) u16 lA[4096];
  __shared__ __align__(16) u16 lB[4096];
  const int tid = threadIdx.x, wave = tid >> 6, lane = tid & 63;
  const int quad = lane >> 4, l16 = lane & 15;
  const int row0 = blockIdx.y * 128, col0 = blockIdx.x * 128;
  const int wm = (wave >> 1) * 64, wn = (wave & 1) * 64;
  const u16* A = (col0 < 256) ? xb : yb;

  f32x4 acc[4][4];
  #pragma unroll
  for (int i = 0; i < 4; i++)
    #pragma unroll
    for (int j = 0; j < 4; j++) acc[i][j] = fzero4();

  for (int k0 = 0; k0 < 1024; k0 += 32) {
    __syncthreads();
    #pragma unroll
    for (int i = 0; i < 4; i++) {
      int inst = wave * 4 + i;
      if (inst < 8) {
        int c = inst * 64 + lane;
        glds16(A + (size_t)(row0 + (c & 127)) * 1024 + k0 + (c >> 7) * 8, lA + inst * 512);
      } else {
        int i2 = inst - 8;
        int c = i2 * 64 + lane;
        glds16(wt + (size_t)(col0 + (c & 127)) * 1024 + k0 + (c >> 7) * 8, lB + i2 * 512);
      }
    }
    __syncthreads();
    bf16x8 af[4], bfr[4];
    #pragma unroll
    for (int mi = 0; mi < 4; mi++)
      af[mi] = *(const bf16x8*)(lA + (quad * 128 + wm + mi * 16 + l16) * 8);
    #pragma unroll
    for (int ni = 0; ni < 4; ni++)
      bfr[ni] = *(const bf16x8*)(lB + (quad * 128 + wn + ni * 16 + l16) * 8);
    #pragma unroll
    for (int mi = 0; mi < 4; mi++)
      #pragma unroll
      for (int ni = 0; ni < 4; ni++)
        acc[mi][ni] = __builtin_amdgcn_mfma_f32_16x16x32_bf16(af[mi], bfr[ni], acc[mi][ni], 0, 0, 0);
  }

  #pragma unroll
  for (int mi = 0; mi < 4; mi++)
    #pragma unroll
    for (int ni = 0; ni < 4; ni++) {
      int col = col0 + wn + ni * 16 + l16;
      float bvv;
      if (col < 256) bvv = bq[col];
      else if (col < 512) bvv = bk[col - 256];
      else bvv = bv[col - 512];
      #pragma unroll
      for (int r = 0; r < 4; r++) {
        int row = row0 + wm + mi * 16 + quad * 4 + r;
        float v = acc[mi][ni][r] + bvv;
        if (col < 256) {
          fb[(size_t)row * 256 + col] = f2bf(v);
        } else if (col < 512) {
          gb[(size_t)row * 256 + (col - 256)] = f2bf(v);
        } else {
          int c3 = col - 512;
          int bb = row >> 11, mloc = row & 2047;
          int head = c3 >> 7, dv = c3 & 127;
          ht[((size_t)((bb * 8 + head) * 128 + dv)) * 2048 + mloc] = f2bf(v);
        }
      }
    }
}

// ---------------- flash attention (no-max softmax, S^T trick) ----------------
// Grid: (M/128, H, B). Block: 512 threads (8 waves, 16 Q-rows each).
__global__ __launch_bounds__(512, 4)
void attn_kernel(const u16* __restrict__ fb, const u16* __restrict__ gb,
                 const u16* __restrict__ ht, const float* __restrict__ x,
                 const float* __restrict__ gamma, float* __restrict__ out) {
  __shared__ __align__(16) u16 lK[4096];        // 8KB  K tile: 128n x 32d
  __shared__ __align__(16) u16 lV[16384];       // 32KB V tile: 128n x 128dv (V^T chunks)
  __shared__ __align__(16) u16 lP[8 * 2112];    // 33KB per-wave P [16m][132]
  const int tid = threadIdx.x, wave = tid >> 6, lane = tid & 63;
  const int quad = lane >> 4, l16 = lane & 15;
  const int m0 = blockIdx.x * 128;
  const int head = blockIdx.y, b = blockIdx.z;

  // Q fragment (A/B layout): row = m0+wave*16+l16, d = quad*8..+8, pre-scaled
  const float sscale = 0.17677669529663687f * 1.4426950408889634f;  // 1/sqrt(32)*log2(e)
  const int qrow = m0 + wave * 16 + l16;
  bf16x8 qf;
  {
    union { bf16x8 v; u16 s[8]; } q;
    q.v = *(const bf16x8*)(fb + ((size_t)(b * 2048 + qrow) * 256 + head * 32 + quad * 8));
    #pragma unroll
    for (int j = 0; j < 8; j++) {
      float f = __uint_as_float((u32)q.s[j] << 16) * sscale;
      q.s[j] = f2bf(f);
    }
    qf = q.v;
  }

  f32x4 oacc[8];
  #pragma unroll
  for (int t = 0; t < 8; t++) oacc[t] = fzero4();
  float lsum = 0.f;

  u16* pw = lP + wave * 2112;

  for (int n0 = 0; n0 < 2048; n0 += 128) {
    __syncthreads();
    #pragma unroll
    for (int i = 0; i < 5; i++) {
      int inst = wave * 5 + i;
      if (inst < 8) {
        int c = inst * 64 + lane;
        glds16(gb + ((size_t)(b * 2048 + n0 + (c & 127)) * 256 + head * 32 + (c >> 7) * 8),
               lK + inst * 512);
      } else {
        int i2 = inst - 8;
        int c = i2 * 64 + lane;
        glds16(ht + ((size_t)((b * 8 + head) * 128 + (c & 127)) * 2048 + n0 + (c >> 7) * 8),
               lV + i2 * 512);
      }
    }
    __syncthreads();

    // S^T = K Q^T : rows n = t*16+quad*4+r, col m = l16
    float pv[8][4];
    #pragma unroll
    for (int t = 0; t < 8; t++) {
      bf16x8 kf = *(const bf16x8*)(lK + (quad * 128 + t * 16 + l16) * 8);
      f32x4 s = __builtin_amdgcn_mfma_f32_16x16x32_bf16(kf, qf, fzero4(), 0, 0, 0);
      #pragma unroll
      for (int r = 0; r < 4; r++) {
        float sv = s[r];
        float v = fmaxf(sv, 0.2f * sv);   // leaky-relu (scale pre-folded into Q)
#if __has_builtin(__builtin_amdgcn_exp2f)
        float p = __builtin_amdgcn_exp2f(v);
#else
        float p = exp2f(v);
#endif
        pv[t][r] = p;
        lsum += p;
      }
    }

    // pack P (truncating bf16) and write rows [m=l16][n], 4 consecutive n per write
    #pragma unroll
    for (int t = 0; t < 8; t++) {
      u32 lo = pack_bf_trunc(pv[t][1], pv[t][0]);
      u32 hi = pack_bf_trunc(pv[t][3], pv[t][2]);
      *(uint2*)(pw + l16 * 132 + t * 16 + quad * 4) = make_uint2(lo, hi);
    }

    // PV: A-frag of P at [m=l16][k=kt*32+quad*8]
    #pragma unroll
    for (int kt = 0; kt < 4; kt++) {
      bf16x8 pf = *(const bf16x8*)(pw + l16 * 132 + kt * 32 + quad * 8);
      #pragma unroll
      for (int tdv = 0; tdv < 8; tdv++) {
        bf16x8 vf = *(const bf16x8*)(lV + ((kt * 4 + quad) * 128 + tdv * 16 + l16) * 8);
        oacc[tdv] = __builtin_amdgcn_mfma_f32_16x16x32_bf16(pf, vf, oacc[tdv], 0, 0, 0);
      }
    }
  }

  // finish row sums: lane's lsum covers m=l16 over its n subset; reduce across quads
  lsum += __shfl_xor(lsum, 16, 64);
  lsum += __shfl_xor(lsum, 32, 64);
  // rowsum for C-layout row quad*4+r lives at lane l16==quad*4+r
  const float gam = gamma[0];
  float invl[4];
  #pragma unroll
  for (int r = 0; r < 4; r++) invl[r] = 1.0f / __shfl(lsum, quad * 4 + r, 64);

  #pragma unroll
  for (int tdv = 0; tdv < 8; tdv++)
    #pragma unroll
    for (int r = 0; r < 4; r++) {
      int row = m0 + wave * 16 + quad * 4 + r;
      int col = head * 128 + tdv * 16 + l16;
      size_t idx = ((size_t)(b * 2048 + row)) * 1024 + col;
      out[idx] = gam * (oacc[tdv][r] * invl[r]) + x[idx];
    }
}

extern "C" void kernel_launch(void* const* d_in, const int* in_sizes, int n_in,
                              void* d_out, int out_size, void* d_ws, size_t ws_size,
                              hipStream_t stream) {
  const float* x     = (const float*)d_in[0];
  const float* y     = (const float*)d_in[1];
  const float* Wq    = (const float*)d_in[2];
  const float* bq    = (const float*)d_in[3];
  const float* Wk    = (const float*)d_in[4];
  const float* bk    = (const float*)d_in[5];
  const float* Wv    = (const float*)d_in[6];
  const float* bv    = (const float*)d_in[7];
  const float* gamma = (const float*)d_in[8];
  float* out = (float*)d_out;

  char* ws = (char*)d_ws;
  u16* xb = (u16*)(ws);                 // 16 MB  [B*M][1024]
  u16* yb = (u16*)(ws + 16777216);      // 16 MB
  u16* wt = (u16*)(ws + 33554432);      // 3 MB   [1536][1024]  (Wq^T|Wk^T|Wv^T)
  u16* fb = (u16*)(ws + 36700160);      // 4 MB   [B*M][256]
  u16* gb = (u16*)(ws + 40894464);      // 4 MB
  u16* ht = (u16*)(ws + 45088768);      // 16 MB  [B][H][DV][M]

  cvt_kernel<<<16384, 256, 0, stream>>>(x, xb, y, yb, 2097152);
  transcvt_kernel<<<dim3(8, 32), 256, 0, stream>>>(Wq, wt, 1024, 256);
  transcvt_kernel<<<dim3(8, 32), 256, 0, stream>>>(Wk, wt + 256 * 1024, 1024, 256);
  transcvt_kernel<<<dim3(32, 32), 256, 0, stream>>>(Wv, wt + 512 * 1024, 1024, 1024);
  gemm_all_kernel<<<dim3(12, 64), 256, 0, stream>>>(xb, yb, wt, bq, bk, bv, fb, gb, ht);
  attn_kernel<<<dim3(16, 8, 4), 512, 0, stream>>>(fb, gb, ht, x, gamma, out);
}

// Round 3
// 285.277 us; speedup vs baseline: 1.2577x; 1.0215x over previous
//
#include <hip/hip_runtime.h>
#include <cstdint>
#include <cstddef>

typedef unsigned short u16;
typedef unsigned int u32;
typedef __attribute__((ext_vector_type(8))) short bf16x8;
typedef __attribute__((ext_vector_type(4))) float f32x4;

__device__ __forceinline__ u16 f2bf(float f) {
  union { float f; unsigned int u; } v; v.f = f;
  unsigned int r = v.u + 0x7fffu + ((v.u >> 16) & 1u);
  return (u16)(r >> 16);
}

__device__ __forceinline__ u32 pack_bf_trunc(float hi, float lo) {
#if __has_builtin(__builtin_amdgcn_perm)
  return __builtin_amdgcn_perm(__float_as_uint(hi), __float_as_uint(lo), 0x07060302u);
#else
  return (__float_as_uint(hi) & 0xffff0000u) | (__float_as_uint(lo) >> 16);
#endif
}

__device__ __forceinline__ void glds16(const void* g, void* l) {
  __builtin_amdgcn_global_load_lds(
      (const __attribute__((address_space(1))) unsigned int*)g,
      (__attribute__((address_space(3))) unsigned int*)l, 16, 0, 0);
}

__device__ __forceinline__ f32x4 fzero4() { f32x4 z = {0.f, 0.f, 0.f, 0.f}; return z; }

// ---------------- prep: cvt x,y -> bf16 AND transpose-convert weights ----------------
// grid 1D: blocks [0,16384) do x/y cvt (float4 each thread);
// blocks [16384, 16384+1536) do 32x32 transpose tiles of Wq|Wk|Wv into wt.
__global__ void prep_kernel(const float* __restrict__ x, u16* __restrict__ xb,
                            const float* __restrict__ y, u16* __restrict__ yb,
                            const float* __restrict__ Wq, const float* __restrict__ Wk,
                            const float* __restrict__ Wv, u16* __restrict__ wt) {
  __shared__ float tile[32][33];
  int bx = blockIdx.x;
  if (bx < 16384) {
    int i = bx * 256 + threadIdx.x;
    const float* src; u16* dst;
    if (i < 2097152) { src = x; dst = xb; }
    else             { src = y; dst = yb; i -= 2097152; }
    float4 v = ((const float4*)src)[i];
    ushort4 o = make_ushort4(f2bf(v.x), f2bf(v.y), f2bf(v.z), f2bf(v.w));
    ((ushort4*)dst)[i] = o;
    return;
  }
  int t = bx - 16384;
  const float* in; u16* out; int N, tn;
  if (t < 256)      { in = Wq; out = wt;              N = 256;  tn = t; }
  else if (t < 512) { in = Wk; out = wt + 256 * 1024; N = 256;  tn = t - 256; }
  else              { in = Wv; out = wt + 512 * 1024; N = 1024; tn = t - 512; }
  int ntiles = N >> 5;
  int n0 = (tn % ntiles) * 32, k0 = (tn / ntiles) * 32;
  int tx = threadIdx.x & 31, ty = threadIdx.x >> 5;
  #pragma unroll
  for (int j = ty; j < 32; j += 8) tile[j][tx] = in[(size_t)(k0 + j) * N + n0 + tx];
  __syncthreads();
  #pragma unroll
  for (int j = ty; j < 32; j += 8) out[(size_t)(n0 + j) * 1024 + k0 + tx] = f2bf(tile[tx][j]);
}

// ---------------- fused projection GEMM ----------------
// out tiles over [8192][1536]: cols 0-255 -> fb (Q), 256-511 -> gb (K),
// 512-1535 -> ht (V, stored [b][head][dv][m]).
__global__ __launch_bounds__(256, 3)
void gemm_all_kernel(const u16* __restrict__ xb, const u16* __restrict__ yb,
                     const u16* __restrict__ wt,
                     const float* __restrict__ bq, const float* __restrict__ bk,
                     const float* __restrict__ bv,
                     u16* __restrict__ fb, u16* __restrict__ gb, u16* __restrict__ ht) {
  __shared__ __align__(16) u16 lA[4096];
  __shared__ __align__(16) u16 lB[4096];
  const int tid = threadIdx.x, wave = tid >> 6, lane = tid & 63;
  const int quad = lane >> 4, l16 = lane & 15;
  const int row0 = blockIdx.y * 128, col0 = blockIdx.x * 128;
  const int wm = (wave >> 1) * 64, wn = (wave & 1) * 64;
  const u16* A = (col0 < 256) ? xb : yb;

  f32x4 acc[4][4];
  #pragma unroll
  for (int i = 0; i < 4; i++)
    #pragma unroll
    for (int j = 0; j < 4; j++) acc[i][j] = fzero4();

  for (int k0 = 0; k0 < 1024; k0 += 32) {
    __syncthreads();
    #pragma unroll
    for (int i = 0; i < 4; i++) {
      int inst = wave * 4 + i;
      if (inst < 8) {
        int c = inst * 64 + lane;
        glds16(A + (size_t)(row0 + (c & 127)) * 1024 + k0 + (c >> 7) * 8, lA + inst * 512);
      } else {
        int i2 = inst - 8;
        int c = i2 * 64 + lane;
        glds16(wt + (size_t)(col0 + (c & 127)) * 1024 + k0 + (c >> 7) * 8, lB + i2 * 512);
      }
    }
    __syncthreads();
    bf16x8 af[4], bfr[4];
    #pragma unroll
    for (int mi = 0; mi < 4; mi++)
      af[mi] = *(const bf16x8*)(lA + (quad * 128 + wm + mi * 16 + l16) * 8);
    #pragma unroll
    for (int ni = 0; ni < 4; ni++)
      bfr[ni] = *(const bf16x8*)(lB + (quad * 128 + wn + ni * 16 + l16) * 8);
    #pragma unroll
    for (int mi = 0; mi < 4; mi++)
      #pragma unroll
      for (int ni = 0; ni < 4; ni++)
        acc[mi][ni] = __builtin_amdgcn_mfma_f32_16x16x32_bf16(af[mi], bfr[ni], acc[mi][ni], 0, 0, 0);
  }

  #pragma unroll
  for (int mi = 0; mi < 4; mi++)
    #pragma unroll
    for (int ni = 0; ni < 4; ni++) {
      int col = col0 + wn + ni * 16 + l16;
      float bvv;
      if (col < 256) bvv = bq[col];
      else if (col < 512) bvv = bk[col - 256];
      else bvv = bv[col - 512];
      #pragma unroll
      for (int r = 0; r < 4; r++) {
        int row = row0 + wm + mi * 16 + quad * 4 + r;
        float v = acc[mi][ni][r] + bvv;
        if (col < 256) {
          fb[(size_t)row * 256 + col] = f2bf(v);
        } else if (col < 512) {
          gb[(size_t)row * 256 + (col - 256)] = f2bf(v);
        } else {
          int c3 = col - 512;
          int bb = row >> 11, mloc = row & 2047;
          int head = c3 >> 7, dv = c3 & 127;
          ht[((size_t)((bb * 8 + head) * 128 + dv)) * 2048 + mloc] = f2bf(v);
        }
      }
    }
}

// ---------------- flash attention: 32 q-rows/wave, 4-wave blocks ----------------
// Grid: (M/128, H, B). Block: 256 threads. Each wave: rows m0+wave*32 .. +32.
__global__ __launch_bounds__(256, 2)
void attn_kernel(const u16* __restrict__ fb, const u16* __restrict__ gb,
                 const u16* __restrict__ ht, const float* __restrict__ x,
                 const float* __restrict__ gamma, float* __restrict__ out) {
  __shared__ __align__(16) u16 lK[4096];         // 8KB  K tile: 128n x 32d (chunked)
  __shared__ __align__(16) u16 lV[16384];        // 32KB V tile: 128n x 128dv (chunked)
  __shared__ __align__(16) u16 lP[4 * 32 * 136]; // 34KB per-wave P [32m][136]
  const int tid = threadIdx.x, wave = tid >> 6, lane = tid & 63;
  const int quad = lane >> 4, l16 = lane & 15;
  const int m0 = blockIdx.x * 128;
  const int head = blockIdx.y, b = blockIdx.z;
  const int wrow = m0 + wave * 32;

  const float sscale = 0.17677669529663687f * 1.4426950408889634f;  // 1/sqrt(32)*log2(e)
  bf16x8 qf[2];
  #pragma unroll
  for (int mt = 0; mt < 2; mt++) {
    union { bf16x8 v; u16 s[8]; } q;
    q.v = *(const bf16x8*)(fb + ((size_t)(b * 2048 + wrow + mt * 16 + l16) * 256 + head * 32 + quad * 8));
    #pragma unroll
    for (int j = 0; j < 8; j++) {
      float f = __uint_as_float((u32)q.s[j] << 16) * sscale;
      q.s[j] = f2bf(f);
    }
    qf[mt] = q.v;
  }

  f32x4 oacc[2][8];
  #pragma unroll
  for (int mt = 0; mt < 2; mt++)
    #pragma unroll
    for (int t = 0; t < 8; t++) oacc[mt][t] = fzero4();
  float lsum[2] = {0.f, 0.f};

  u16* pw = lP + wave * (32 * 136);

  for (int n0 = 0; n0 < 2048; n0 += 128) {
    __syncthreads();
    #pragma unroll
    for (int i = 0; i < 10; i++) {
      int inst = wave * 10 + i;
      if (inst < 8) {
        int c = inst * 64 + lane;
        glds16(gb + ((size_t)(b * 2048 + n0 + (c & 127)) * 256 + head * 32 + (c >> 7) * 8),
               lK + inst * 512);
      } else {
        int i2 = inst - 8;
        int c = i2 * 64 + lane;
        glds16(ht + ((size_t)((b * 8 + head) * 128 + (c & 127)) * 2048 + n0 + (c >> 7) * 8),
               lV + i2 * 512);
      }
    }
    __syncthreads();

    // S^T = K Q^T for both m-tiles: rows n = t*16+quad*4+r, col m = l16
    #pragma unroll
    for (int t = 0; t < 8; t++) {
      bf16x8 kf = *(const bf16x8*)(lK + (quad * 128 + t * 16 + l16) * 8);
      f32x4 s0 = __builtin_amdgcn_mfma_f32_16x16x32_bf16(kf, qf[0], fzero4(), 0, 0, 0);
      f32x4 s1 = __builtin_amdgcn_mfma_f32_16x16x32_bf16(kf, qf[1], fzero4(), 0, 0, 0);
      float p0[4], p1[4];
      #pragma unroll
      for (int r = 0; r < 4; r++) {
        float v0 = fmaxf(s0[r], 0.2f * s0[r]);
        float v1 = fmaxf(s1[r], 0.2f * s1[r]);
        p0[r] = exp2f(v0); lsum[0] += p0[r];
        p1[r] = exp2f(v1); lsum[1] += p1[r];
      }
      *(uint2*)(pw + l16 * 136 + t * 16 + quad * 4) =
          make_uint2(pack_bf_trunc(p0[1], p0[0]), pack_bf_trunc(p0[3], p0[2]));
      *(uint2*)(pw + (16 + l16) * 136 + t * 16 + quad * 4) =
          make_uint2(pack_bf_trunc(p1[1], p1[0]), pack_bf_trunc(p1[3], p1[2]));
    }

    // PV: each vf feeds both m-tiles
    #pragma unroll
    for (int kt = 0; kt < 4; kt++) {
      bf16x8 pf0 = *(const bf16x8*)(pw + l16 * 136 + kt * 32 + quad * 8);
      bf16x8 pf1 = *(const bf16x8*)(pw + (16 + l16) * 136 + kt * 32 + quad * 8);
      #pragma unroll
      for (int tdv = 0; tdv < 8; tdv++) {
        bf16x8 vf = *(const bf16x8*)(lV + ((kt * 4 + quad) * 128 + tdv * 16 + l16) * 8);
        oacc[0][tdv] = __builtin_amdgcn_mfma_f32_16x16x32_bf16(pf0, vf, oacc[0][tdv], 0, 0, 0);
        oacc[1][tdv] = __builtin_amdgcn_mfma_f32_16x16x32_bf16(pf1, vf, oacc[1][tdv], 0, 0, 0);
      }
    }
  }

  const float gam = gamma[0];
  #pragma unroll
  for (int mt = 0; mt < 2; mt++) {
    float ls = lsum[mt];
    ls += __shfl_xor(ls, 16, 64);
    ls += __shfl_xor(ls, 32, 64);
    float invl[4];
    #pragma unroll
    for (int r = 0; r < 4; r++) invl[r] = 1.0f / __shfl(ls, quad * 4 + r, 64);
    #pragma unroll
    for (int tdv = 0; tdv < 8; tdv++)
      #pragma unroll
      for (int r = 0; r < 4; r++) {
        int row = wrow + mt * 16 + quad * 4 + r;
        int col = head * 128 + tdv * 16 + l16;
        size_t idx = ((size_t)(b * 2048 + row)) * 1024 + col;
        out[idx] = gam * (oacc[mt][tdv][r] * invl[r]) + x[idx];
      }
  }
}

extern "C" void kernel_launch(void* const* d_in, const int* in_sizes, int n_in,
                              void* d_out, int out_size, void* d_ws, size_t ws_size,
                              hipStream_t stream) {
  const float* x     = (const float*)d_in[0];
  const float* y     = (const float*)d_in[1];
  const float* Wq    = (const float*)d_in[2];
  const float* bq    = (const float*)d_in[3];
  const float* Wk    = (const float*)d_in[4];
  const float* bk    = (const float*)d_in[5];
  const float* Wv    = (const float*)d_in[6];
  const float* bv    = (const float*)d_in[7];
  const float* gamma = (const float*)d_in[8];
  float* out = (float*)d_out;

  char* ws = (char*)d_ws;
  u16* xb = (u16*)(ws);                 // 16 MB  [B*M][1024]
  u16* yb = (u16*)(ws + 16777216);      // 16 MB
  u16* wt = (u16*)(ws + 33554432);      // 3 MB   [1536][1024]  (Wq^T|Wk^T|Wv^T)
  u16* fb = (u16*)(ws + 36700160);      // 4 MB   [B*M][256]
  u16* gb = (u16*)(ws + 40894464);      // 4 MB
  u16* ht = (u16*)(ws + 45088768);      // 16 MB  [B][H][DV][M]

  prep_kernel<<<16384 + 1536, 256, 0, stream>>>(x, xb, y, yb, Wq, Wk, Wv, wt);
  gemm_all_kernel<<<dim3(12, 64), 256, 0, stream>>>(xb, yb, wt, bq, bk, bv, fb, gb, ht);
  attn_kernel<<<dim3(16, 8, 4), 256, 0, stream>>>(fb, gb, ht, x, gamma, out);
}

// Round 4
// 279.902 us; speedup vs baseline: 1.2818x; 1.0192x over previous
//
#include <hip/hip_runtime.h>
#include <cstdint>
#include <cstddef>

typedef unsigned short u16;
typedef unsigned int u32;
typedef __attribute__((ext_vector_type(8))) short bf16x8;
typedef __attribute__((ext_vector_type(4))) float f32x4;

__device__ __forceinline__ u16 f2bf(float f) {
  union { float f; unsigned int u; } v; v.f = f;
  unsigned int r = v.u + 0x7fffu + ((v.u >> 16) & 1u);
  return (u16)(r >> 16);
}

__device__ __forceinline__ u32 pack_bf_trunc(float hi, float lo) {
#if __has_builtin(__builtin_amdgcn_perm)
  return __builtin_amdgcn_perm(__float_as_uint(hi), __float_as_uint(lo), 0x07060302u);
#else
  return (__float_as_uint(hi) & 0xffff0000u) | (__float_as_uint(lo) >> 16);
#endif
}

__device__ __forceinline__ void glds16(const void* g, void* l) {
  __builtin_amdgcn_global_load_lds(
      (const __attribute__((address_space(1))) unsigned int*)g,
      (__attribute__((address_space(3))) unsigned int*)l, 16, 0, 0);
}

__device__ __forceinline__ f32x4 fzero4() { f32x4 z = {0.f, 0.f, 0.f, 0.f}; return z; }

// ---------------- prep: cvt x,y -> bf16 AND transpose-convert weights ----------------
__global__ void prep_kernel(const float* __restrict__ x, u16* __restrict__ xb,
                            const float* __restrict__ y, u16* __restrict__ yb,
                            const float* __restrict__ Wq, const float* __restrict__ Wk,
                            const float* __restrict__ Wv, u16* __restrict__ wt) {
  __shared__ float tile[32][33];
  int bx = blockIdx.x;
  if (bx < 16384) {
    int i = bx * 256 + threadIdx.x;
    const float* src; u16* dst;
    if (i < 2097152) { src = x; dst = xb; }
    else             { src = y; dst = yb; i -= 2097152; }
    float4 v = ((const float4*)src)[i];
    ushort4 o = make_ushort4(f2bf(v.x), f2bf(v.y), f2bf(v.z), f2bf(v.w));
    ((ushort4*)dst)[i] = o;
    return;
  }
  int t = bx - 16384;
  const float* in; u16* out; int N, tn;
  if (t < 256)      { in = Wq; out = wt;              N = 256;  tn = t; }
  else if (t < 512) { in = Wk; out = wt + 256 * 1024; N = 256;  tn = t - 256; }
  else              { in = Wv; out = wt + 512 * 1024; N = 1024; tn = t - 512; }
  int ntiles = N >> 5;
  int n0 = (tn % ntiles) * 32, k0 = (tn / ntiles) * 32;
  int tx = threadIdx.x & 31, ty = threadIdx.x >> 5;
  #pragma unroll
  for (int j = ty; j < 32; j += 8) tile[j][tx] = in[(size_t)(k0 + j) * N + n0 + tx];
  __syncthreads();
  #pragma unroll
  for (int j = ty; j < 32; j += 8) out[(size_t)(n0 + j) * 1024 + k0 + tx] = f2bf(tile[tx][j]);
}

// ---------------- fused projection GEMM (BK=64, coalesced V-transpose epilogue) ------
// out tiles over [8192][1536]: cols 0-255 -> fb (Q), 256-511 -> gb (K),
// 512-1535 -> ht (V, stored [b][head][dv][m] via LDS transpose).
__global__ __launch_bounds__(256, 3)
void gemm_all_kernel(const u16* __restrict__ xb, const u16* __restrict__ yb,
                     const u16* __restrict__ wt,
                     const float* __restrict__ bq, const float* __restrict__ bk,
                     const float* __restrict__ bv,
                     u16* __restrict__ fb, u16* __restrict__ gb, u16* __restrict__ ht) {
  __shared__ __align__(16) u16 ls[17408];   // 34.8 KB: staging (32 KB) / transpose (34.8 KB)
  u16* lA = ls;          // 8192 u16: A tile 128r x 64k, chunked [k/8][row]
  u16* lB = ls + 8192;   // 8192 u16: B tile
  const int tid = threadIdx.x, lane = tid & 63;
  const int quad = lane >> 4, l16 = lane & 15;
  const int wave = tid >> 6;
  const int row0 = blockIdx.y * 128, col0 = blockIdx.x * 128;
  const int wm = (wave >> 1) * 64, wn = (wave & 1) * 64;
  const u16* A = (col0 < 256) ? xb : yb;

  f32x4 acc[4][4];
  #pragma unroll
  for (int i = 0; i < 4; i++)
    #pragma unroll
    for (int j = 0; j < 4; j++) acc[i][j] = fzero4();

  for (int k0 = 0; k0 < 1024; k0 += 64) {
    __syncthreads();
    #pragma unroll
    for (int i = 0; i < 4; i++) {
      int c = i * 256 + tid;
      glds16(A + (size_t)(row0 + (c & 127)) * 1024 + k0 + (c >> 7) * 8, lA + c * 8);
    }
    #pragma unroll
    for (int i = 0; i < 4; i++) {
      int c = i * 256 + tid;
      glds16(wt + (size_t)(col0 + (c & 127)) * 1024 + k0 + (c >> 7) * 8, lB + c * 8);
    }
    __syncthreads();
    #pragma unroll
    for (int kk = 0; kk < 2; kk++) {
      bf16x8 af[4], bfr[4];
      #pragma unroll
      for (int mi = 0; mi < 4; mi++)
        af[mi] = *(const bf16x8*)(lA + ((kk * 4 + quad) * 128 + wm + mi * 16 + l16) * 8);
      #pragma unroll
      for (int ni = 0; ni < 4; ni++)
        bfr[ni] = *(const bf16x8*)(lB + ((kk * 4 + quad) * 128 + wn + ni * 16 + l16) * 8);
      #pragma unroll
      for (int mi = 0; mi < 4; mi++)
        #pragma unroll
        for (int ni = 0; ni < 4; ni++)
          acc[mi][ni] = __builtin_amdgcn_mfma_f32_16x16x32_bf16(af[mi], bfr[ni], acc[mi][ni], 0, 0, 0);
    }
  }

  if (col0 < 512) {
    // Q / K epilogue: direct stores
    #pragma unroll
    for (int mi = 0; mi < 4; mi++)
      #pragma unroll
      for (int ni = 0; ni < 4; ni++) {
        int col = col0 + wn + ni * 16 + l16;
        float bvv = (col < 256) ? bq[col] : bk[col - 256];
        #pragma unroll
        for (int r = 0; r < 4; r++) {
          int row = row0 + wm + mi * 16 + quad * 4 + r;
          float v = acc[mi][ni][r] + bvv;
          if (col < 256) fb[(size_t)row * 256 + col] = f2bf(v);
          else           gb[(size_t)row * 256 + (col - 256)] = f2bf(v);
        }
      }
  } else {
    // V epilogue: transpose through LDS, coalesced stores to ht[b][head][dv][m]
    const int headblk = (col0 - 512) >> 7;
    const int bb = row0 >> 11, mloc0 = row0 & 2047;
    __syncthreads();  // staging reads done; reuse ls
    #pragma unroll
    for (int mi = 0; mi < 4; mi++)
      #pragma unroll
      for (int ni = 0; ni < 4; ni++) {
        int col = wn + ni * 16 + l16;             // block-local dv
        int rowl = wm + mi * 16 + quad * 4;       // block-local m
        float bvv = bv[(col0 - 512) + col];
        float v0 = acc[mi][ni][0] + bvv, v1 = acc[mi][ni][1] + bvv;
        float v2 = acc[mi][ni][2] + bvv, v3 = acc[mi][ni][3] + bvv;
        *(uint2*)(ls + col * 136 + rowl) =
            make_uint2(pack_bf_trunc(v1, v0), pack_bf_trunc(v3, v2));
      }
    __syncthreads();
    int dv = tid >> 1, half = tid & 1;
    const u16* src = ls + dv * 136 + half * 64;
    u16* dst = ht + ((size_t)((bb * 8 + headblk) * 128 + dv)) * 2048 + mloc0 + half * 64;
    #pragma unroll
    for (int i = 0; i < 8; i++)
      ((uint4*)dst)[i] = ((const uint4*)src)[i];
  }
}

// ---------------- flash attention (round-2 proven: 512 thr, 16 rows/wave) ----------------
__global__ __launch_bounds__(512, 4)
void attn_kernel(const u16* __restrict__ fb, const u16* __restrict__ gb,
                 const u16* __restrict__ ht, const float* __restrict__ x,
                 const float* __restrict__ gamma, float* __restrict__ out) {
  __shared__ __align__(16) u16 lK[4096];        // 8KB  K tile: 128n x 32d
  __shared__ __align__(16) u16 lV[16384];       // 32KB V tile: 128n x 128dv (V^T chunks)
  __shared__ __align__(16) u16 lP[8 * 2112];    // 33KB per-wave P [16m][132]
  const int tid = threadIdx.x, wave = tid >> 6, lane = tid & 63;
  const int quad = lane >> 4, l16 = lane & 15;
  const int m0 = blockIdx.x * 128;
  const int head = blockIdx.y, b = blockIdx.z;

  const float sscale = 0.17677669529663687f * 1.4426950408889634f;  // 1/sqrt(32)*log2(e)
  const int qrow = m0 + wave * 16 + l16;
  bf16x8 qf;
  {
    union { bf16x8 v; u16 s[8]; } q;
    q.v = *(const bf16x8*)(fb + ((size_t)(b * 2048 + qrow) * 256 + head * 32 + quad * 8));
    #pragma unroll
    for (int j = 0; j < 8; j++) {
      float f = __uint_as_float((u32)q.s[j] << 16) * sscale;
      q.s[j] = f2bf(f);
    }
    qf = q.v;
  }

  f32x4 oacc[8];
  #pragma unroll
  for (int t = 0; t < 8; t++) oacc[t] = fzero4();
  float lsum = 0.f;

  u16* pw = lP + wave * 2112;

  for (int n0 = 0; n0 < 2048; n0 += 128) {
    __syncthreads();
    #pragma unroll
    for (int i = 0; i < 5; i++) {
      int inst = wave * 5 + i;
      if (inst < 8) {
        int c = inst * 64 + lane;
        glds16(gb + ((size_t)(b * 2048 + n0 + (c & 127)) * 256 + head * 32 + (c >> 7) * 8),
               lK + inst * 512);
      } else {
        int i2 = inst - 8;
        int c = i2 * 64 + lane;
        glds16(ht + ((size_t)((b * 8 + head) * 128 + (c & 127)) * 2048 + n0 + (c >> 7) * 8),
               lV + i2 * 512);
      }
    }
    __syncthreads();

    // S^T = K Q^T : rows n = t*16+quad*4+r, col m = l16
    float pv[8][4];
    #pragma unroll
    for (int t = 0; t < 8; t++) {
      bf16x8 kf = *(const bf16x8*)(lK + (quad * 128 + t * 16 + l16) * 8);
      f32x4 s = __builtin_amdgcn_mfma_f32_16x16x32_bf16(kf, qf, fzero4(), 0, 0, 0);
      #pragma unroll
      for (int r = 0; r < 4; r++) {
        float sv = s[r];
        float v = fmaxf(sv, 0.2f * sv);   // leaky-relu (scale pre-folded into Q)
        float p = exp2f(v);
        pv[t][r] = p;
        lsum += p;
      }
    }

    // pack P (truncating bf16) and write rows [m=l16][n], 4 consecutive n per write
    #pragma unroll
    for (int t = 0; t < 8; t++) {
      u32 lo = pack_bf_trunc(pv[t][1], pv[t][0]);
      u32 hi = pack_bf_trunc(pv[t][3], pv[t][2]);
      *(uint2*)(pw + l16 * 132 + t * 16 + quad * 4) = make_uint2(lo, hi);
    }

    // PV: A-frag of P at [m=l16][k=kt*32+quad*8]
    #pragma unroll
    for (int kt = 0; kt < 4; kt++) {
      bf16x8 pf = *(const bf16x8*)(pw + l16 * 132 + kt * 32 + quad * 8);
      #pragma unroll
      for (int tdv = 0; tdv < 8; tdv++) {
        bf16x8 vf = *(const bf16x8*)(lV + ((kt * 4 + quad) * 128 + tdv * 16 + l16) * 8);
        oacc[tdv] = __builtin_amdgcn_mfma_f32_16x16x32_bf16(pf, vf, oacc[tdv], 0, 0, 0);
      }
    }
  }

  lsum += __shfl_xor(lsum, 16, 64);
  lsum += __shfl_xor(lsum, 32, 64);
  const float gam = gamma[0];
  float invl[4];
  #pragma unroll
  for (int r = 0; r < 4; r++) invl[r] = 1.0f / __shfl(lsum, quad * 4 + r, 64);

  #pragma unroll
  for (int tdv = 0; tdv < 8; tdv++)
    #pragma unroll
    for (int r = 0; r < 4; r++) {
      int row = m0 + wave * 16 + quad * 4 + r;
      int col = head * 128 + tdv * 16 + l16;
      size_t idx = ((size_t)(b * 2048 + row)) * 1024 + col;
      out[idx] = gam * (oacc[tdv][r] * invl[r]) + x[idx];
    }
}

extern "C" void kernel_launch(void* const* d_in, const int* in_sizes, int n_in,
                              void* d_out, int out_size, void* d_ws, size_t ws_size,
                              hipStream_t stream) {
  const float* x     = (const float*)d_in[0];
  const float* y     = (const float*)d_in[1];
  const float* Wq    = (const float*)d_in[2];
  const float* bq    = (const float*)d_in[3];
  const float* Wk    = (const float*)d_in[4];
  const float* bk    = (const float*)d_in[5];
  const float* Wv    = (const float*)d_in[6];
  const float* bv    = (const float*)d_in[7];
  const float* gamma = (const float*)d_in[8];
  float* out = (float*)d_out;

  char* ws = (char*)d_ws;
  u16* xb = (u16*)(ws);                 // 16 MB  [B*M][1024]
  u16* yb = (u16*)(ws + 16777216);      // 16 MB
  u16* wt = (u16*)(ws + 33554432);      // 3 MB   [1536][1024]  (Wq^T|Wk^T|Wv^T)
  u16* fb = (u16*)(ws + 36700160);      // 4 MB   [B*M][256]
  u16* gb = (u16*)(ws + 40894464);      // 4 MB
  u16* ht = (u16*)(ws + 45088768);      // 16 MB  [B][H][DV][M]

  prep_kernel<<<16384 + 1536, 256, 0, stream>>>(x, xb, y, yb, Wq, Wk, Wv, wt);
  gemm_all_kernel<<<dim3(12, 64), 256, 0, stream>>>(xb, yb, wt, bq, bk, bv, fb, gb, ht);
  attn_kernel<<<dim3(16, 8, 4), 512, 0, stream>>>(fb, gb, ht, x, gamma, out);
}